// Round 13
// baseline (232.785 us; speedup 1.0000x reference)
//
#include <hip/hip_runtime.h>
#include <hip/hip_bf16.h>
#include <cstdint>
#include <cstddef>

typedef unsigned short u16;
typedef __bf16 bf16x8 __attribute__((ext_vector_type(8)));
typedef float f32x4 __attribute__((ext_vector_type(4)));
typedef unsigned int u32x4 __attribute__((ext_vector_type(4)));  // clang vec: ok for nontemporal builtins

#define EPSF 1e-5f

__device__ __forceinline__ float b2f(u16 u) {
  unsigned int i = ((unsigned int)u) << 16;
  return __builtin_bit_cast(float, i);
}
__device__ __forceinline__ u16 f2b(float f) {
  unsigned int u = __builtin_bit_cast(unsigned int, f);
  u = u + 0x7fffu + ((u >> 16) & 1u);  // round-to-nearest-even
  return (u16)(u >> 16);
}

// async global->LDS, 16B/lane.
__device__ __forceinline__ void async_load16(const u16* g, u16* l) {
  __builtin_amdgcn_global_load_lds(
      (__attribute__((address_space(1))) void*)(g),
      (__attribute__((address_space(3))) void*)(l), 16, 0, 0);
}

// ---------------- kernel 1: fused prep (build_f | A-convert+deg | thetaT) --
// r13: role B (the long pole) dispatches FIRST and is split 2x finer
// (2048 blocks x 128 m) for load balance with the light role-A blocks.
__global__ __launch_bounds__(256) void prep_kernel(
    const void* __restrict__ X, const void* __restrict__ A,
    const void* __restrict__ Th, u16* __restrict__ Abf, u16* __restrict__ Ft,
    float* __restrict__ deg, float* __restrict__ logd, u16* __restrict__ ThT) {
  __shared__ int sbad;
  __shared__ float Xl[128 * 13];
  __shared__ float red[4];
  const int tid = threadIdx.x;
  if (tid == 0) sbad = 0;
  __syncthreads();
  {
    const u16* Xu = (const u16*)X;
    int bad = 0;
#pragma unroll
    for (int q = 0; q < 8; ++q) {
      float a = fabsf(b2f(Xu[q * 256 + tid]));
      if (!(a <= 1e4f)) bad = 1;  // huge or NaN -> fp32 storage
    }
    if (bad) atomicOr(&sbad, 1);
  }
  __syncthreads();
  const int isf32 = sbad;
  const int bid = blockIdx.x;

  if (bid < 2048) {
    // ---- role B: build F^T [12288][2048] bf16; 128 m-rows per block
    const int blk = bid;             // b*512 + ch*16 + mc
    const int mc = blk & 15;
    const int ch = (blk >> 4) & 31;
    const int b  = blk >> 9;
    const size_t g0 = ((size_t)(b * 32 + ch) * 2048 + (size_t)mc * 128) * 12;
    if (isf32) {
      const float4* Xg = (const float4*)((const float*)X + g0);
#pragma unroll
      for (int q = 0; q < 2; ++q) {
        const int id = q * 256 + tid;        // 0..511, need < 384 float4s
        if (id < 384) {
          const float4 v = Xg[id];
          const int j = id * 4, row = j / 12, col = j % 12;  // col in {0,4,8}
          Xl[row * 13 + col]     = v.x;
          Xl[row * 13 + col + 1] = v.y;
          Xl[row * 13 + col + 2] = v.z;
          Xl[row * 13 + col + 3] = v.w;
        }
      }
    } else {
      const u16* Xg = (const u16*)X + g0;
#pragma unroll
      for (int q = 0; q < 6; ++q) {
        const int id = q * 256 + tid;        // 0..1535 u16s
        Xl[(id / 12) * 13 + id % 12] = b2f(Xg[id]);
      }
    }
    __syncthreads();
    const int m = tid & 127;
    const int ph = tid >> 7;                 // p-half: 0..1
    const int gm = mc * 128 + m;
#pragma unroll
    for (int pj = 0; pj < 6; ++pj) {
      const int p = ph * 6 + pj;
      const float x = Xl[m * 13 + p];
      const float x2 = x * x, x3 = x2 * x, x4 = x2 * x2;
      const float e = __expf(x), en = __expf(-x);
      const float vals[8] = {x, x2, x3, x4, x * e, e, x * en, en};
      const size_t cb = (size_t)(b * 12 + p) * 256 + ch;
#pragma unroll
      for (int f = 0; f < 8; ++f)
        Ft[(cb + (size_t)f * 32) * 2048 + gm] = f2b(vals[f]);
    }
  } else if (bid < 4096) {
    // ---- role A: convert A row -> bf16 AND compute degree in one pass
    const int row = bid - 2048;
    float s = 0.f;
    uint4 st;
    if (isf32) {
      const float4* Af = (const float4*)A + (size_t)row * 512 + tid * 2;
      float4 a = Af[0], b = Af[1];
      s = a.x + a.y + a.z + a.w + b.x + b.y + b.z + b.w;
      u16 o[8] = {f2b(a.x), f2b(a.y), f2b(a.z), f2b(a.w),
                  f2b(b.x), f2b(b.y), f2b(b.z), f2b(b.w)};
      st = *(const uint4*)o;
    } else {
      st = ((const uint4*)A)[(size_t)row * 256 + tid];
      const u16* o = (const u16*)&st;
#pragma unroll
      for (int k = 0; k < 8; ++k) s += b2f(o[k]);
    }
    *(uint4*)(Abf + (size_t)row * 2048 + tid * 8) = st;
#pragma unroll
    for (int off = 32; off > 0; off >>= 1) s += __shfl_down(s, off, 64);
    const int lane = tid & 63, w = tid >> 6;
    if (lane == 0) red[w] = s;
    __syncthreads();
    if (tid == 0) {
      float t = red[0] + red[1] + red[2] + red[3];
      deg[row] = t;
      logd[row] = logf(t + 1.f);
    }
  } else {
    // ---- role C: Theta transpose -> ThT [32][672]
    const int e = (bid - 4096) * 256 + tid;
    if (e < 21504) {
      const int k = e >> 5, o = e & 31;
      ThT[o * 672 + k] = isf32 ? f2b(((const float*)Th)[e]) : ((const u16*)Th)[e];
    }
  }
}

// ---------------- kernel 2: GEMM Y = Abf @ F (FROZEN r9: ~103us, ~1000TF) --
// XCD partition: 4 bm x 48 bn rectangle per XCD, bm-fastest -> FETCH 117MB.
__global__ __launch_bounds__(256) void gemm_kernel(const u16* __restrict__ A,
                                                   const u16* __restrict__ Ft,
                                                   u16* __restrict__ Y) {
  __shared__ __attribute__((aligned(16))) u16 smem[2 * 128 * 64];  // 32 KB
  u16* As = smem;             // [128][64]
  u16* Bs = smem + 128 * 64;  // [128][64]
  const int tid = threadIdx.x;
  const int wave = tid >> 6;
  const int lane = tid & 63;
  const int l15 = lane & 15;
  const int quad = lane >> 4;
  const int wm = wave >> 1;
  const int wn = wave & 1;

  const int i4 = blockIdx.x;         // 0..1535
  const int xcd = i4 & 7;
  const int s4 = i4 >> 3;            // 0..191
  const int bm = (xcd >> 1) * 4 + (s4 & 3);
  const int bn = (xcd & 1) * 48 + (s4 >> 2);

  const int lrow = lane >> 3;                    // 0..7
  const int schunk = (lane & 7) ^ lrow;          // swizzled source chunk
  const u16* gA = A  + (size_t)(bm * 128 + wave * 32 + lrow) * 2048 + schunk * 8;
  const u16* gB = Ft + (size_t)(bn * 128 + wave * 32 + lrow) * 2048 + schunk * 8;
  u16* lA = As + wave * 32 * 64 + lane * 8;  // per-lane dest (base + lane*16B)
  u16* lB = Bs + wave * 32 * 64 + lane * 8;

  f32x4 acc[4][4];
#pragma unroll
  for (int i = 0; i < 4; ++i)
#pragma unroll
    for (int j = 0; j < 4; ++j) acc[i][j] = (f32x4){0.f, 0.f, 0.f, 0.f};

  for (int kk = 0; kk < 2048; kk += 64) {
    __syncthreads();  // prev iter's LDS reads done before overwrite
#pragma unroll
    for (int i = 0; i < 4; ++i) {
      async_load16(gA + (size_t)i * (8 * 2048) + kk, lA + i * (8 * 64));
      async_load16(gB + (size_t)i * (8 * 2048) + kk, lB + i * (8 * 64));
    }
    __syncthreads();  // compiler drains vmcnt(0) before s_barrier
#pragma unroll
    for (int ks = 0; ks < 2; ++ks) {
      const int ca = ((ks * 4 + quad) ^ (l15 & 7)) * 8;  // un-swizzle chunk
      bf16x8 af[4], bfr[4];
#pragma unroll
      for (int t = 0; t < 4; ++t)
        af[t] = *(const bf16x8*)(As + (wm * 64 + t * 16 + l15) * 64 + ca);
#pragma unroll
      for (int t = 0; t < 4; ++t)
        bfr[t] = *(const bf16x8*)(Bs + (wn * 64 + t * 16 + l15) * 64 + ca);
#pragma unroll
      for (int mt = 0; mt < 4; ++mt)
#pragma unroll
        for (int nt = 0; nt < 4; ++nt)
          acc[mt][nt] = __builtin_amdgcn_mfma_f32_16x16x32_bf16(af[mt], bfr[nt],
                                                                acc[mt][nt], 0, 0, 0);
    }
  }

  __syncthreads();  // all K-loop LDS reads complete before aliasing
  u16* Cs = smem;   // [128][128] u16 = 32 KB
#pragma unroll
  for (int mt = 0; mt < 4; ++mt)
#pragma unroll
    for (int nt = 0; nt < 4; ++nt) {
      const int row = wm * 64 + mt * 16 + quad * 4;
      const int col = wn * 64 + nt * 16 + l15;
#pragma unroll
      for (int j = 0; j < 4; ++j)
        Cs[(row + j) * 128 + col] = f2b(acc[mt][nt][j]);
    }
  __syncthreads();
  const size_t ybase = (size_t)(bm * 128) * 12288 + (size_t)bn * 128;
#pragma unroll
  for (int q = 0; q < 8; ++q) {
    const int id = q * 256 + tid;           // 0..2047
    const int r = id >> 4, c = (id & 15) * 8;
    __builtin_nontemporal_store(*(const u32x4*)(Cs + r * 128 + c),
                                (u32x4*)(Y + ybase + (size_t)r * 12288 + c));
  }
}

// ---------------- kernel 3: epilogue v5 (4 blocks/CU) ----------------------
// r13: pz quarters (3 p's each) -> 1024 blocks = 4/CU for latency hiding.
__global__ __launch_bounds__(256) void epilogue_kernel(
    const u16* __restrict__ Y, const u16* __restrict__ Fx,
    const float* __restrict__ deg, const float* __restrict__ logd,
    const u16* __restrict__ ThT, const void* __restrict__ Bias,
    void* __restrict__ out, const u16* __restrict__ Xu) {
  __shared__ __attribute__((aligned(16))) u16 Ys[32 * 264];
  __shared__ u16 Xs[32 * 33];
  __shared__ __attribute__((aligned(16))) u16 feats[32 * 680];
  __shared__ int sbad;
  __shared__ float red[4];
  const int tid = threadIdx.x;
  if (tid == 0) sbad = 0;
  __syncthreads();
  float ls = 0.f;
  {
    int bad = 0;
#pragma unroll
    for (int q = 0; q < 8; ++q) {
      float a = fabsf(b2f(Xu[q * 256 + tid]));
      if (!(a <= 1e4f)) bad = 1;
      ls += logd[q * 256 + tid];
    }
    if (bad) atomicOr(&sbad, 1);
  }
#pragma unroll
  for (int off = 32; off > 0; off >>= 1) ls += __shfl_down(ls, off, 64);
  if ((tid & 63) == 0) red[tid >> 6] = ls;
  __syncthreads();
  const int isf32 = sbad;
  const float delta = (red[0] + red[1] + red[2] + red[3]) * (1.0f / 2048.0f);

  const int nc = blockIdx.x;   // 0..63 node chunk
  const int b  = blockIdx.y;   // 0..3
  const int pz = blockIdx.z;   // 0..3 (3 p's each)

  const int nl = tid >> 3;     // 0..31 local node
  const int chg = tid & 7;     // 4 channels each
  const int inode = nc * 32 + nl;
  const float d = fmaxf(deg[inode], EPSF);
  const float rd = 1.0f / d;
  const float s = logd[inode] / delta;
  const float is = 1.0f / fmaxf(s, EPSF);

  const int wave = tid >> 6, lane = tid & 63;
  const int l15 = lane & 15, quad = lane >> 4;
  const int mt = wave >> 1, nt = wave & 1;  // 2x2 of 16x16
  const int o = nt * 16 + l15;
  const float bias = isf32 ? ((const float*)Bias)[o] : b2f(((const u16*)Bias)[o]);

  float r[4][3];

#pragma unroll
  for (int pp = 0; pp < 3; ++pp) {
    const int p = pz * 3 + pp;
    const int bp = b * 12 + p;
    __syncthreads();  // prior iter's LDS reads complete
#pragma unroll
    for (int q = 0; q < 4; ++q) {
      const int id = q * 256 + tid;                 // 0..1023
      const int rr = id >> 5, ck = id & 31;
      *(u32x4*)(Ys + rr * 264 + ck * 8) = __builtin_nontemporal_load(
          (const u32x4*)(Y + (size_t)(nc * 32 + rr) * 12288 + (size_t)bp * 256 + ck * 8));
      Xs[rr * 33 + ck] = Fx[(size_t)(bp * 256 + rr) * 2048 + nc * 32 + ck];
    }
    __syncthreads();

    const u16* yr = Ys + nl * 264;
#pragma unroll
    for (int cc = 0; cc < 4; ++cc) {
      const int ch = chg * 4 + cc;
      const float m1 = b2f(yr[ch]) * rd;
      const float m2 = b2f(yr[32 + ch]) * rd;
      const float m3 = b2f(yr[64 + ch]) * rd;
      const float m4 = b2f(yr[96 + ch]) * rd;
      const float smx = b2f(yr[128 + ch]) / (b2f(yr[160 + ch]) + EPSF);
      const float smn = b2f(yr[192 + ch]) / (b2f(yr[224 + ch]) + EPSF);
      const float x = b2f(Xs[ch * 33 + nl]);
      const float var = fmaxf(m2 - m1 * m1, 0.f);
      const float stdv = sqrtf(var + EPSF);
      const float x2 = x * x, x3 = x2 * x, x4 = x2 * x2;
      const float dist = x2 - 2.f * x * m1 + m2;
      const float ed2 = x4 - 4.f * x3 * m1 + 6.f * x2 * m2 - 4.f * x * m3 + m4;
      const float dstd = sqrtf(fmaxf(ed2 - dist * dist, 0.f) + EPSF);
      const float f7[7] = {smn, smx, m1, stdv, var, dist, dstd};
#pragma unroll
      for (int a = 0; a < 7; ++a) {
        const int k = a * 32 + ch;
        feats[nl * 680 + k]       = f2b(f7[a]);
        feats[nl * 680 + 224 + k] = f2b(f7[a] * s);
        feats[nl * 680 + 448 + k] = f2b(f7[a] * is);
      }
    }
    __syncthreads();

    f32x4 acc = (f32x4){0.f, 0.f, 0.f, 0.f};
#pragma unroll
    for (int kt = 0; kt < 21; ++kt) {  // K = 672
      bf16x8 a  = *(const bf16x8*)(feats + (mt * 16 + l15) * 680 + kt * 32 + quad * 8);
      bf16x8 bb = *(const bf16x8*)(ThT + (size_t)o * 672 + kt * 32 + quad * 8);
      acc = __builtin_amdgcn_mfma_f32_16x16x32_bf16(a, bb, acc, 0, 0, 0);
    }
#pragma unroll
    for (int j = 0; j < 4; ++j) r[j][pp] = acc[j];
  }

#pragma unroll
  for (int j = 0; j < 4; ++j) {
    const int node = mt * 16 + quad * 4 + j;
    const int ig = nc * 32 + node;
    const size_t oi = ((size_t)(b * 32 + o) * 2048 + ig) * 12 + pz * 3;
#pragma unroll
    for (int k = 0; k < 3; ++k) {
      float t = r[j][k] + bias;
      t = t > 0.f ? t : 0.01f * t;   // leaky_relu
      if (isf32) ((float*)out)[oi + k] = t;
      else       ((u16*)out)[oi + k]   = f2b(t);
    }
  }
}

// ---------------------------------------------------------------------------
extern "C" void kernel_launch(void* const* d_in, const int* in_sizes, int n_in,
                              void* d_out, int out_size, void* d_ws, size_t ws_size,
                              hipStream_t stream) {
  const void* X    = d_in[0];
  const void* A    = d_in[1];
  const void* Th   = d_in[2];
  const void* Bias = d_in[3];
  char* ws = (char*)d_ws;

  u16*   Ft   = (u16*)(ws);                       // 12288*2048*2 = 50331648
  u16*   Y    = (u16*)(ws + 50331648);            // 2048*12288*2 = 50331648
  u16*   Abf  = (u16*)(ws + 100663296);           // 2048*2048*2  = 8388608
  float* deg  = (float*)(ws + 109051904);         // 8192
  float* logd = (float*)(ws + 109060096);         // 8192
  u16*   ThT  = (u16*)(ws + 109068288);           // 43008

  prep_kernel<<<4180, 256, 0, stream>>>(X, A, Th, Abf, Ft, deg, logd, ThT);
  gemm_kernel<<<1536, 256, 0, stream>>>(Abf, Ft, Y);
  epilogue_kernel<<<dim3(64, 4, 4), 256, 0, stream>>>(Y, Ft, deg, logd, ThT,
                                                      Bias, d_out, (const u16*)X);
}

// Round 14
// 214.873 us; speedup vs baseline: 1.0834x; 1.0834x over previous
//
#include <hip/hip_runtime.h>
#include <hip/hip_bf16.h>
#include <cstdint>
#include <cstddef>

typedef unsigned short u16;
typedef __bf16 bf16x8 __attribute__((ext_vector_type(8)));
typedef float f32x4 __attribute__((ext_vector_type(4)));
typedef unsigned int u32x4 __attribute__((ext_vector_type(4)));  // clang vec: ok for nontemporal builtins

#define EPSF 1e-5f

__device__ __forceinline__ float b2f(u16 u) {
  unsigned int i = ((unsigned int)u) << 16;
  return __builtin_bit_cast(float, i);
}
__device__ __forceinline__ u16 f2b(float f) {
  unsigned int u = __builtin_bit_cast(unsigned int, f);
  u = u + 0x7fffu + ((u >> 16) & 1u);  // round-to-nearest-even
  return (u16)(u >> 16);
}

// async global->LDS, 16B/lane.
__device__ __forceinline__ void async_load16(const u16* g, u16* l) {
  __builtin_amdgcn_global_load_lds(
      (__attribute__((address_space(1))) void*)(g),
      (__attribute__((address_space(3))) void*)(l), 16, 0, 0);
}

// ---------------- kernel 1: fused prep (A-convert+deg | build_f | thetaT) --
__global__ __launch_bounds__(256) void prep_kernel(
    const void* __restrict__ X, const void* __restrict__ A,
    const void* __restrict__ Th, u16* __restrict__ Abf, u16* __restrict__ Ft,
    float* __restrict__ deg, float* __restrict__ logd, u16* __restrict__ ThT) {
  __shared__ int sbad;
  __shared__ float Xl[256 * 13];
  __shared__ float red[4];
  const int tid = threadIdx.x;
  if (tid == 0) sbad = 0;
  __syncthreads();
  {
    const u16* Xu = (const u16*)X;
    int bad = 0;
#pragma unroll
    for (int q = 0; q < 8; ++q) {
      float a = fabsf(b2f(Xu[q * 256 + tid]));
      if (!(a <= 1e4f)) bad = 1;  // huge or NaN
    }
    if (bad) atomicOr(&sbad, 1);
  }
  __syncthreads();
  const int isf32 = sbad;
  const int bid = blockIdx.x;

  if (bid < 2048) {
    // ---- role A: convert A row -> bf16 AND compute degree in one pass
    const int row = bid;
    float s = 0.f;
    uint4 st;
    if (isf32) {
      const float4* Af = (const float4*)A + (size_t)row * 512 + tid * 2;
      float4 a = Af[0], b = Af[1];
      s = a.x + a.y + a.z + a.w + b.x + b.y + b.z + b.w;
      u16 o[8] = {f2b(a.x), f2b(a.y), f2b(a.z), f2b(a.w),
                  f2b(b.x), f2b(b.y), f2b(b.z), f2b(b.w)};
      st = *(const uint4*)o;
    } else {
      st = ((const uint4*)A)[(size_t)row * 256 + tid];
      const u16* o = (const u16*)&st;
#pragma unroll
      for (int k = 0; k < 8; ++k) s += b2f(o[k]);
    }
    *(uint4*)(Abf + (size_t)row * 2048 + tid * 8) = st;
#pragma unroll
    for (int off = 32; off > 0; off >>= 1) s += __shfl_down(s, off, 64);
    const int lane = tid & 63, w = tid >> 6;
    if (lane == 0) red[w] = s;
    __syncthreads();
    if (tid == 0) {
      float t = red[0] + red[1] + red[2] + red[3];
      deg[row] = t;
      logd[row] = logf(t + 1.f);
    }
  } else if (bid < 3072) {
    // ---- role B: build F^T [12288][2048] bf16
    const int blk = bid - 2048;      // b*256 + ch*8 + mc
    const int mc = blk & 7;
    const int ch = (blk >> 3) & 31;
    const int b  = blk >> 8;
    const size_t g0 = ((size_t)(b * 32 + ch) * 2048 + (size_t)mc * 256) * 12;
    if (isf32) {
      const float4* Xg = (const float4*)((const float*)X + g0);
#pragma unroll
      for (int q = 0; q < 3; ++q) {
        const int id = q * 256 + tid;        // 0..767 float4s
        const float4 v = Xg[id];
        const int j = id * 4, row = j / 12, col = j % 12;  // col in {0,4,8}
        Xl[row * 13 + col]     = v.x;
        Xl[row * 13 + col + 1] = v.y;
        Xl[row * 13 + col + 2] = v.z;
        Xl[row * 13 + col + 3] = v.w;
      }
    } else {
      const u16* Xg = (const u16*)X + g0;
#pragma unroll
      for (int q = 0; q < 12; ++q) {
        const int id = q * 256 + tid;        // 0..3071 u16s
        Xl[(id / 12) * 13 + id % 12] = b2f(Xg[id]);
      }
    }
    __syncthreads();
    const int m = tid;
    const int gm = mc * 256 + m;
#pragma unroll
    for (int p = 0; p < 12; ++p) {
      const float x = Xl[m * 13 + p];
      const float x2 = x * x, x3 = x2 * x, x4 = x2 * x2;
      const float e = __expf(x), en = __expf(-x);
      const float vals[8] = {x, x2, x3, x4, x * e, e, x * en, en};
      const size_t cb = (size_t)(b * 12 + p) * 256 + ch;
#pragma unroll
      for (int f = 0; f < 8; ++f)
        Ft[(cb + (size_t)f * 32) * 2048 + gm] = f2b(vals[f]);
    }
  } else {
    // ---- role C: Theta transpose -> ThT [32][672]
    const int e = (bid - 3072) * 256 + tid;
    if (e < 21504) {
      const int k = e >> 5, o = e & 31;
      ThT[o * 672 + k] = isf32 ? f2b(((const float*)Th)[e]) : ((const u16*)Th)[e];
    }
  }
}

// ---------------- kernel 2: GEMM Y = Abf @ F (FROZEN r9: ~103us, ~1000TF) ---
// XCD partition: 4 bm x 48 bn rectangle per XCD, bm-fastest -> FETCH 117MB.
__global__ __launch_bounds__(256) void gemm_kernel(const u16* __restrict__ A,
                                                   const u16* __restrict__ Ft,
                                                   u16* __restrict__ Y) {
  __shared__ __attribute__((aligned(16))) u16 smem[2 * 128 * 64];  // 32 KB
  u16* As = smem;             // [128][64]
  u16* Bs = smem + 128 * 64;  // [128][64]
  const int tid = threadIdx.x;
  const int wave = tid >> 6;
  const int lane = tid & 63;
  const int l15 = lane & 15;
  const int quad = lane >> 4;
  const int wm = wave >> 1;
  const int wn = wave & 1;

  const int i4 = blockIdx.x;         // 0..1535
  const int xcd = i4 & 7;
  const int s4 = i4 >> 3;            // 0..191
  const int bm = (xcd >> 1) * 4 + (s4 & 3);
  const int bn = (xcd & 1) * 48 + (s4 >> 2);

  const int lrow = lane >> 3;                    // 0..7
  const int schunk = (lane & 7) ^ lrow;          // swizzled source chunk
  const u16* gA = A  + (size_t)(bm * 128 + wave * 32 + lrow) * 2048 + schunk * 8;
  const u16* gB = Ft + (size_t)(bn * 128 + wave * 32 + lrow) * 2048 + schunk * 8;
  u16* lA = As + wave * 32 * 64 + lane * 8;  // per-lane dest (base + lane*16B)
  u16* lB = Bs + wave * 32 * 64 + lane * 8;

  f32x4 acc[4][4];
#pragma unroll
  for (int i = 0; i < 4; ++i)
#pragma unroll
    for (int j = 0; j < 4; ++j) acc[i][j] = (f32x4){0.f, 0.f, 0.f, 0.f};

  for (int kk = 0; kk < 2048; kk += 64) {
    __syncthreads();  // prev iter's LDS reads done before overwrite
#pragma unroll
    for (int i = 0; i < 4; ++i) {
      async_load16(gA + (size_t)i * (8 * 2048) + kk, lA + i * (8 * 64));
      async_load16(gB + (size_t)i * (8 * 2048) + kk, lB + i * (8 * 64));
    }
    __syncthreads();  // compiler drains vmcnt(0) before s_barrier
#pragma unroll
    for (int ks = 0; ks < 2; ++ks) {
      const int ca = ((ks * 4 + quad) ^ (l15 & 7)) * 8;  // un-swizzle chunk
      bf16x8 af[4], bfr[4];
#pragma unroll
      for (int t = 0; t < 4; ++t)
        af[t] = *(const bf16x8*)(As + (wm * 64 + t * 16 + l15) * 64 + ca);
#pragma unroll
      for (int t = 0; t < 4; ++t)
        bfr[t] = *(const bf16x8*)(Bs + (wn * 64 + t * 16 + l15) * 64 + ca);
#pragma unroll
      for (int mt = 0; mt < 4; ++mt)
#pragma unroll
        for (int nt = 0; nt < 4; ++nt)
          acc[mt][nt] = __builtin_amdgcn_mfma_f32_16x16x32_bf16(af[mt], bfr[nt],
                                                                acc[mt][nt], 0, 0, 0);
    }
  }

  __syncthreads();  // all K-loop LDS reads complete before aliasing
  u16* Cs = smem;   // [128][128] u16 = 32 KB
#pragma unroll
  for (int mt = 0; mt < 4; ++mt)
#pragma unroll
    for (int nt = 0; nt < 4; ++nt) {
      const int row = wm * 64 + mt * 16 + quad * 4;
      const int col = wn * 64 + nt * 16 + l15;
#pragma unroll
      for (int j = 0; j < 4; ++j)
        Cs[(row + j) * 128 + col] = f2b(acc[mt][nt][j]);
    }
  __syncthreads();
  const size_t ybase = (size_t)(bm * 128) * 12288 + (size_t)bn * 128;
#pragma unroll
  for (int q = 0; q < 8; ++q) {
    const int id = q * 256 + tid;           // 0..2047
    const int r = id >> 4, c = (id & 15) * 8;
    __builtin_nontemporal_store(*(const u32x4*)(Cs + r * 128 + c),
                                (u32x4*)(Y + ybase + (size_t)r * 12288 + c));
  }
}

// ---------------- kernel 3: epilogue v3 + self-detect + self-delta ---------
__global__ __launch_bounds__(256) void epilogue_kernel(
    const u16* __restrict__ Y, const u16* __restrict__ Fx,
    const float* __restrict__ deg, const float* __restrict__ logd,
    const u16* __restrict__ ThT, const void* __restrict__ Bias,
    void* __restrict__ out, const u16* __restrict__ Xu) {
  __shared__ __attribute__((aligned(16))) u16 Ys[32 * 264];
  __shared__ u16 Xs[32 * 33];
  __shared__ __attribute__((aligned(16))) u16 feats[32 * 680];
  __shared__ int sbad;
  __shared__ float red[4];
  const int tid = threadIdx.x;
  if (tid == 0) sbad = 0;
  __syncthreads();
  float ls = 0.f;
  {
    int bad = 0;
#pragma unroll
    for (int q = 0; q < 8; ++q) {
      float a = fabsf(b2f(Xu[q * 256 + tid]));
      if (!(a <= 1e4f)) bad = 1;
      ls += logd[q * 256 + tid];
    }
    if (bad) atomicOr(&sbad, 1);
  }
#pragma unroll
  for (int off = 32; off > 0; off >>= 1) ls += __shfl_down(ls, off, 64);
  if ((tid & 63) == 0) red[tid >> 6] = ls;
  __syncthreads();
  const int isf32 = sbad;
  const float delta = (red[0] + red[1] + red[2] + red[3]) * (1.0f / 2048.0f);

  const int nc = blockIdx.x;   // 0..63 node chunk
  const int b  = blockIdx.y;   // 0..3
  const int pz = blockIdx.z;   // 0..1

  const int nl = tid >> 3;     // 0..31 local node
  const int chg = tid & 7;     // 4 channels each
  const int inode = nc * 32 + nl;
  const float d = fmaxf(deg[inode], EPSF);
  const float rd = 1.0f / d;
  const float s = logd[inode] / delta;
  const float is = 1.0f / fmaxf(s, EPSF);

  const int wave = tid >> 6, lane = tid & 63;
  const int l15 = lane & 15, quad = lane >> 4;
  const int mt = wave >> 1, nt = wave & 1;  // 2x2 of 16x16
  const int o = nt * 16 + l15;
  const float bias = isf32 ? ((const float*)Bias)[o] : b2f(((const u16*)Bias)[o]);

  float r[4][6];

#pragma unroll
  for (int pp = 0; pp < 6; ++pp) {
    const int p = pz * 6 + pp;
    const int bp = b * 12 + p;
    __syncthreads();  // prior iter's LDS reads complete
#pragma unroll
    for (int q = 0; q < 4; ++q) {
      const int id = q * 256 + tid;                 // 0..1023
      const int rr = id >> 5, ck = id & 31;
      *(u32x4*)(Ys + rr * 264 + ck * 8) = __builtin_nontemporal_load(
          (const u32x4*)(Y + (size_t)(nc * 32 + rr) * 12288 + (size_t)bp * 256 + ck * 8));
      Xs[rr * 33 + ck] = Fx[(size_t)(bp * 256 + rr) * 2048 + nc * 32 + ck];
    }
    __syncthreads();

    const u16* yr = Ys + nl * 264;
#pragma unroll
    for (int cc = 0; cc < 4; ++cc) {
      const int ch = chg * 4 + cc;
      const float m1 = b2f(yr[ch]) * rd;
      const float m2 = b2f(yr[32 + ch]) * rd;
      const float m3 = b2f(yr[64 + ch]) * rd;
      const float m4 = b2f(yr[96 + ch]) * rd;
      const float smx = b2f(yr[128 + ch]) / (b2f(yr[160 + ch]) + EPSF);
      const float smn = b2f(yr[192 + ch]) / (b2f(yr[224 + ch]) + EPSF);
      const float x = b2f(Xs[ch * 33 + nl]);
      const float var = fmaxf(m2 - m1 * m1, 0.f);
      const float stdv = sqrtf(var + EPSF);
      const float x2 = x * x, x3 = x2 * x, x4 = x2 * x2;
      const float dist = x2 - 2.f * x * m1 + m2;
      const float ed2 = x4 - 4.f * x3 * m1 + 6.f * x2 * m2 - 4.f * x * m3 + m4;
      const float dstd = sqrtf(fmaxf(ed2 - dist * dist, 0.f) + EPSF);
      const float f7[7] = {smn, smx, m1, stdv, var, dist, dstd};
#pragma unroll
      for (int a = 0; a < 7; ++a) {
        const int k = a * 32 + ch;
        feats[nl * 680 + k]       = f2b(f7[a]);
        feats[nl * 680 + 224 + k] = f2b(f7[a] * s);
        feats[nl * 680 + 448 + k] = f2b(f7[a] * is);
      }
    }
    __syncthreads();

    f32x4 acc = (f32x4){0.f, 0.f, 0.f, 0.f};
#pragma unroll
    for (int kt = 0; kt < 21; ++kt) {  // K = 672
      bf16x8 a  = *(const bf16x8*)(feats + (mt * 16 + l15) * 680 + kt * 32 + quad * 8);
      bf16x8 bb = *(const bf16x8*)(ThT + (size_t)o * 672 + kt * 32 + quad * 8);
      acc = __builtin_amdgcn_mfma_f32_16x16x32_bf16(a, bb, acc, 0, 0, 0);
    }
#pragma unroll
    for (int j = 0; j < 4; ++j) r[j][pp] = acc[j];
  }

#pragma unroll
  for (int j = 0; j < 4; ++j) {
    const int node = mt * 16 + quad * 4 + j;
    const int ig = nc * 32 + node;
    const size_t oi = ((size_t)(b * 32 + o) * 2048 + ig) * 12 + pz * 6;
    float v[6];
#pragma unroll
    for (int k = 0; k < 6; ++k) {
      float t = r[j][k] + bias;
      v[k] = t > 0.f ? t : 0.01f * t;   // leaky_relu
    }
    if (isf32) {
      float* dst = (float*)out + oi;   // 8B-aligned
      *(float2*)(dst)     = (float2){v[0], v[1]};
      *(float2*)(dst + 2) = (float2){v[2], v[3]};
      *(float2*)(dst + 4) = (float2){v[4], v[5]};
    } else {
      u16* dst = (u16*)out + oi;
#pragma unroll
      for (int k = 0; k < 6; ++k) dst[k] = f2b(v[k]);
    }
  }
}

// ---------------------------------------------------------------------------
extern "C" void kernel_launch(void* const* d_in, const int* in_sizes, int n_in,
                              void* d_out, int out_size, void* d_ws, size_t ws_size,
                              hipStream_t stream) {
  const void* X    = d_in[0];
  const void* A    = d_in[1];
  const void* Th   = d_in[2];
  const void* Bias = d_in[3];
  char* ws = (char*)d_ws;

  u16*   Ft   = (u16*)(ws);                       // 12288*2048*2 = 50331648
  u16*   Y    = (u16*)(ws + 50331648);            // 2048*12288*2 = 50331648
  u16*   Abf  = (u16*)(ws + 100663296);           // 2048*2048*2  = 8388608
  float* deg  = (float*)(ws + 109051904);         // 8192
  float* logd = (float*)(ws + 109060096);         // 8192
  u16*   ThT  = (u16*)(ws + 109068288);           // 43008

  prep_kernel<<<3156, 256, 0, stream>>>(X, A, Th, Abf, Ft, deg, logd, ThT);
  gemm_kernel<<<1536, 256, 0, stream>>>(Abf, Ft, Y);
  epilogue_kernel<<<dim3(64, 4, 2), 256, 0, stream>>>(Y, Ft, deg, logd, ThT,
                                                      Bias, d_out, (const u16*)X);
}